// Round 7
// baseline (647.636 us; speedup 1.0000x reference)
//
#include <hip/hip_runtime.h>
#include <math.h>

#define EPSB 1e-5f

// Bi=128 Bc=64 T=32 C=300 OQK=75 H=128 LAT=1024
// Padded stacked o-dim (512): q [0,96) (75 real), k [96,192) (75 real), v [192,512) (300 real)
// Packed MFMA operand layout (per image): [ot=32][ks=10][plane=2][lane=64][8] ushort
//   element (o=16*ot+lr, c=32*ks+8*kg+e), lane=kg*16+lr
// ws layout (float offsets):
static const long OFS_BASE  = 0;                      // 128*128
static const long OFS_BALL  = 16384;                  // 128*512
static const long OFS_MEAN  = 81920;                  // 128*1024
static const long OFS_CAPB  = 212992;                 // capP: 64*20480 ushort = 655360 floats
static const long OFS_RAWP  = 868352;                 // kall: 128*327680 ushort = 20,971,520 floats
static const long OFS_X     = 21839872;               // 128*64*300
static const long OFS_H1    = OFS_RAWP;               // alias (kall dead after k_attn7)

using bf16x8 = __attribute__((ext_vector_type(8))) __bf16;
using f32x4  = __attribute__((ext_vector_type(4))) float;
#define MFMA16(a, b, c) __builtin_amdgcn_mfma_f32_16x16x32_bf16(a, b, c, 0, 0, 0)

__device__ inline ushort f2bf(float f) {
  const unsigned u = __float_as_uint(f);
  return (ushort)((u + 0x7FFFu + ((u >> 16) & 1u)) >> 16);
}
__device__ inline float bf2f(ushort h) { return __uint_as_float(((unsigned)h) << 16); }

// ---------------- K1a: img_mean over 36 regions ----------------
__global__ void k_mean(const float* __restrict__ img, float* __restrict__ mean) {
  const int idx = blockIdx.x * 256 + threadIdx.x;      // 131072 total
  const int i = idx >> 10, l = idx & 1023;
  const float* p = img + (size_t)i * 36 * 1024 + l;
  float s = 0.f;
#pragma unroll
  for (int r = 0; r < 36; ++r) s += p[r * 1024];
  mean[idx] = s * (1.0f / 36.0f);
}

// ---------------- K1b: base = mean @ adapt_W^T + adapt_b ----------------
__global__ void k_base(const float* __restrict__ mean, const float* __restrict__ W,
                       const float* __restrict__ b, float* __restrict__ base) {
  __shared__ float m_s[1024];
  const int i = blockIdx.x, tid = threadIdx.x;   // 128 threads
  for (int k = 0; k < 8; ++k) m_s[tid + 128 * k] = mean[i * 1024 + tid + 128 * k];
  __syncthreads();
  float acc = b[tid];
  const float* wr = W + (size_t)tid * 1024;
#pragma unroll 4
  for (int l = 0; l < 1024; ++l) acc = fmaf(m_s[l], wr[l], acc);
  base[i * 128 + tid] = acc;
}

// ---------------- K2b: stacked conv biases ball[i][512] ----------------
__global__ void k_bias(const float* __restrict__ qbW, const float* __restrict__ qbb,
                       const float* __restrict__ kbW, const float* __restrict__ kbb,
                       const float* __restrict__ vbW, const float* __restrict__ vbb,
                       const float* __restrict__ base, float* __restrict__ ball) {
  __shared__ float bs[128];
  const int i = blockIdx.y, tid = threadIdx.x;
  if (tid < 128) bs[tid] = base[i * 128 + tid];
  __syncthreads();
  const int o = blockIdx.x * 256 + tid;
  if (o >= 512) return;
  const float* Wr = nullptr;
  float bb = 0.0f;
  if (o < 75)                   { Wr = qbW + (size_t)o * 128;         bb = qbb[o]; }
  else if (o >= 96 && o < 171)  { Wr = kbW + (size_t)(o - 96) * 128;  bb = kbb[o - 96]; }
  else if (o >= 192 && o < 492) { Wr = vbW + (size_t)(o - 192) * 128; bb = vbb[o - 192]; }
  float acc = 0.0f;
  if (Wr) {
#pragma unroll 4
    for (int h = 0; h < 128; ++h) acc = fmaf(Wr[h], bs[h], acc);
    acc += bb;
  }
  ball[i * 512 + o] = acc;
}

// ---------------- K2c: cap -> packed split-bf16 capP [n][nt=2][ks=10][pl=2][64][8] ----------------
__global__ void __launch_bounds__(256) k_capp(const float* __restrict__ cap,
                                              ushort* __restrict__ capP) {
  __shared__ float ct[32 * 301];
  const int n = blockIdx.x, tid = threadIdx.x;
  const float* capn = cap + (size_t)n * 9600;
  {
    const int r = tid >> 3, c8 = tid & 7;
    for (int m = 0; m < 38; ++m) {
      const int c = c8 + 8 * m;
      if (c < 300) ct[r * 301 + c] = capn[r * 300 + c];
    }
  }
  __syncthreads();
  ushort* dst = capP + (size_t)n * 20480;
  for (int u = 0; u < 10; ++u) {
    const int ul = tid + 256 * u;
    const int unit = ul >> 6, lane = ul & 63;
    const int nt = unit / 20, rem = unit % 20;
    const int ks = rem >> 1, pl = rem & 1;
    const int kg = lane >> 4, lr = lane & 15;
    const int t = nt * 16 + lr;
    ushort o8[8];
#pragma unroll
    for (int e = 0; e < 8; ++e) {
      const int c = 32 * ks + 8 * kg + e;
      const float val = (c < 300) ? ct[t * 301 + c] : 0.f;
      const ushort hi = f2bf(val);
      o8[e] = pl ? f2bf(val - bf2f(hi)) : hi;
    }
    uint4 pk;
    pk.x = (uint)o8[0] | ((uint)o8[1] << 16);
    pk.y = (uint)o8[2] | ((uint)o8[3] << 16);
    pk.z = (uint)o8[4] | ((uint)o8[5] << 16);
    pk.w = (uint)o8[6] | ((uint)o8[7] << 16);
    *reinterpret_cast<uint4*>(dst + unit * 512 + lane * 8) = pk;
  }
}

// ---------------- K3: fused hypernet GEMM + row-BN + split-bf16 pack -> kall ----------------
// Block (g, half): packed row g (0..511), images [half*64, half*64+64).
// GEMM out[c][i] = sum_h W[g-row][c][h] * base[i][h] + bvec[c]; BN stats per i over c<300;
// pack to kall[i][ot=g>>4][ks][pl][kg*16 + (g&15)][e]. Pad rows written as exact zeros.
__global__ void __launch_bounds__(256) k_hyp2(
    const float* __restrict__ qkW, const float* __restrict__ qkb,
    const float* __restrict__ kkW, const float* __restrict__ kkb,
    const float* __restrict__ vkW, const float* __restrict__ vkb,
    const float* __restrict__ qs, const float* __restrict__ qb,
    const float* __restrict__ ks_, const float* __restrict__ kb_,
    const float* __restrict__ vs, const float* __restrict__ vb,
    const float* __restrict__ base, ushort* __restrict__ kall) {
  __shared__ float smem[19200];          // GEMM: bs[128*68]=8704 | Ws at +8704 (320*9=2880); out: [300][64]
  __shared__ float scl[64], shf[64];
  const int g = blockIdx.x, half = blockIdx.y, tid = threadIdx.x;
  const int i0g = half * 64;
  const int ot = g >> 4, lr = g & 15;

  const float* Wb = nullptr;
  const float* bvec = nullptr;
  float bns = 0.f, bnb = 0.f;
  if (g < 75)                    { Wb = qkW + (size_t)g * 38400;          bvec = qkb + g * 300;          bns = qs[g];        bnb = qb[g]; }
  else if (g >= 96 && g < 171)   { Wb = kkW + (size_t)(g - 96) * 38400;   bvec = kkb + (g - 96) * 300;   bns = ks_[g - 96];  bnb = kb_[g - 96]; }
  else if (g >= 192 && g < 492)  { Wb = vkW + (size_t)(g - 192) * 38400;  bvec = vkb + (g - 192) * 300;  bns = vs[g - 192];  bnb = vb[g - 192]; }

  if (!Wb) {  // pad row: exact zeros (P2/P3 rely on them)
    const uint4 z = make_uint4(0, 0, 0, 0);
    for (int m = 0; m < 20; ++m) {
      const int idx = tid + 256 * m;          // 5120 = 64 i x 80 z
      const int ii = idx & 63, zz = idx >> 6;
      const int kg2 = zz & 3, pl = (zz >> 2) & 1, ks2 = zz >> 3;
      const size_t off = (size_t)(i0g + ii) * 327680 +
                         (size_t)(ot * 20 + ks2 * 2 + pl) * 512 + (kg2 * 16 + lr) * 8;
      *reinterpret_cast<uint4*>(kall + off) = z;
    }
    return;
  }

  // stage base^T: bs[h*68 + i]
  for (int m = 0; m < 32; ++m) {
    const int idx = tid + 256 * m;            // 8192
    const int ii = idx >> 7, h = idx & 127;
    smem[h * 68 + ii] = base[(size_t)(i0g + ii) * 128 + h];
  }
  __syncthreads();

  // GEMM: thread (cg=tid>>2, ig=tid&3): 5 c x 16 i
  const int cg = tid >> 2, ig = tid & 3;
  const int c0 = cg * 5, i0 = ig * 16;
  float acc[5][16];
#pragma unroll
  for (int cc = 0; cc < 5; ++cc)
#pragma unroll
    for (int ii = 0; ii < 16; ++ii) acc[cc][ii] = 0.f;
  float* Ws = smem + 8704;
  for (int hc = 0; hc < 16; ++hc) {
    __syncthreads();
    for (int m = 0; m < 10; ++m) {
      const int idx = tid + 256 * m;          // 2560 = 320 c x 8 h
      const int c = idx >> 3, hh = idx & 7;
      Ws[c * 9 + hh] = (c < 300) ? Wb[(size_t)c * 128 + hc * 8 + hh] : 0.f;
    }
    __syncthreads();
#pragma unroll
    for (int hh = 0; hh < 8; ++hh) {
      const int hg = hc * 8 + hh;
      float bvf[16];
#pragma unroll
      for (int u2 = 0; u2 < 4; ++u2) {
        const float4 b4 = *reinterpret_cast<const float4*>(&smem[hg * 68 + i0 + u2 * 4]);
        bvf[u2 * 4 + 0] = b4.x; bvf[u2 * 4 + 1] = b4.y;
        bvf[u2 * 4 + 2] = b4.z; bvf[u2 * 4 + 3] = b4.w;
      }
#pragma unroll
      for (int cc = 0; cc < 5; ++cc) {
        const float wv = Ws[(c0 + cc) * 9 + hh];
#pragma unroll
        for (int ii = 0; ii < 16; ++ii) acc[cc][ii] = fmaf(wv, bvf[ii], acc[cc][ii]);
      }
    }
  }
  __syncthreads();
  // write out[c][i] (+ per-element hypernet bias), reusing smem
#pragma unroll
  for (int cc = 0; cc < 5; ++cc) {
    const int c = c0 + cc;
    if (c < 300) {
      const float bv = bvec[c];
#pragma unroll
      for (int ii = 0; ii < 16; ++ii) smem[c * 64 + i0 + ii] = acc[cc][ii] + bv;
    }
  }
  __syncthreads();
  // BN stats per i over c<300: thread (si=tid>>2, p=tid&3)
  {
    const int si = tid >> 2, p = tid & 3;
    float s1 = 0.f, s2 = 0.f;
    for (int c = p; c < 300; c += 4) {
      const float x = smem[c * 64 + si];
      s1 += x;
      s2 += x * x;
    }
    s1 += __shfl_xor(s1, 1); s2 += __shfl_xor(s2, 1);
    s1 += __shfl_xor(s1, 2); s2 += __shfl_xor(s2, 2);
    const float mu = s1 * (1.0f / 300.0f);
    const float var = s2 * (1.0f / 300.0f) - mu * mu;
    const float scale = bns / sqrtf(var + EPSB);
    if (p == 0) { scl[si] = scale; shf[si] = bnb - mu * scale; }
  }
  __syncthreads();
  // pack: 5120 chunks of 16B
  for (int m = 0; m < 20; ++m) {
    const int idx = tid + 256 * m;
    const int ii = idx & 63, zz = idx >> 6;
    const int kg2 = zz & 3, pl = (zz >> 2) & 1, ks2 = zz >> 3;
    const float sc = scl[ii], sh = shf[ii];
    ushort o8[8];
#pragma unroll
    for (int e = 0; e < 8; ++e) {
      const int c = ks2 * 32 + kg2 * 8 + e;
      float val = 0.f;
      if (c < 300) val = fmaf(smem[c * 64 + ii], sc, sh);
      const ushort hi = f2bf(val);
      o8[e] = pl ? f2bf(val - bf2f(hi)) : hi;
    }
    uint4 pk;
    pk.x = (uint)o8[0] | ((uint)o8[1] << 16);
    pk.y = (uint)o8[2] | ((uint)o8[3] << 16);
    pk.z = (uint)o8[4] | ((uint)o8[5] << 16);
    pk.w = (uint)o8[6] | ((uint)o8[7] << 16);
    const size_t off = (size_t)(i0g + ii) * 327680 +
                       (size_t)(ot * 20 + ks2 * 2 + pl) * 512 + (kg2 * 16 + lr) * 8;
    *reinterpret_cast<uint4*>(kall + off) = pk;
  }
}

// ---------------- K4: fused attention; packed loads + MFMA PV; XCD-swizzled grid ----------------
__global__ void __launch_bounds__(256, 4) k_attn7(
    const float* __restrict__ cap, const ushort* __restrict__ kall,
    const ushort* __restrict__ capP, const float* __restrict__ ball,
    const float* __restrict__ gptr, float* __restrict__ x_all) {
  __shared__ float qk_s[192 * 36];
  __shared__ ushort at_p[2 * 2 * 64 * 8];
  // XCD-aware swizzle: xcd = bid&7 owns images [xcd*16, xcd*16+16), n-major within
  const int bid = blockIdx.x;
  const int xcd = bid & 7, q = bid >> 3;
  const int i = xcd * 16 + (q >> 6), n = q & 63;
  const int tid = threadIdx.x;
  const int lane = tid & 63, w = tid >> 6;
  const int lrow = lane & 15, kg = lane >> 4;
  const float gamma = gptr[0];
  const ushort* kpL = kall + (size_t)i * 327680 + lane * 8;
  const ushort* cpL = capP + (size_t)n * 20480 + lane * 8;
  const float* bal = ball + i * 512;

  // ---- P1: q+k rows [0,192), wave w owns tiles {3w..3w+2}; 2-deep A-prefetch
  {
    f32x4 acc[3][2];
#pragma unroll
    for (int a = 0; a < 3; ++a)
#pragma unroll
      for (int b2 = 0; b2 < 2; ++b2) acc[a][b2] = (f32x4){0.f, 0.f, 0.f, 0.f};
    bf16x8 AhA[3], AlA[3], AhB[3], AlB[3];
#pragma unroll
    for (int mt = 0; mt < 3; ++mt) {
      const ushort* p = kpL + (size_t)((w * 3 + mt) * 20) * 512;
      AhA[mt] = *reinterpret_cast<const bf16x8*>(p);
      AlA[mt] = *reinterpret_cast<const bf16x8*>(p + 512);
    }
#pragma unroll
    for (int kp = 0; kp < 5; ++kp) {
      {
        const int ks = 2 * kp;
        bf16x8 Bh[2], Bl[2];
#pragma unroll
        for (int nt = 0; nt < 2; ++nt) {
          const ushort* p = cpL + (size_t)(nt * 20 + ks * 2) * 512;
          Bh[nt] = *reinterpret_cast<const bf16x8*>(p);
          Bl[nt] = *reinterpret_cast<const bf16x8*>(p + 512);
        }
#pragma unroll
        for (int mt = 0; mt < 3; ++mt) {
          const ushort* p = kpL + (size_t)((w * 3 + mt) * 20 + (ks + 1) * 2) * 512;
          AhB[mt] = *reinterpret_cast<const bf16x8*>(p);
          AlB[mt] = *reinterpret_cast<const bf16x8*>(p + 512);
        }
#pragma unroll
        for (int mt = 0; mt < 3; ++mt)
#pragma unroll
          for (int nt = 0; nt < 2; ++nt) {
            acc[mt][nt] = MFMA16(AhA[mt], Bh[nt], acc[mt][nt]);
            acc[mt][nt] = MFMA16(AhA[mt], Bl[nt], acc[mt][nt]);
            acc[mt][nt] = MFMA16(AlA[mt], Bh[nt], acc[mt][nt]);
          }
      }
      {
        const int ks = 2 * kp + 1;
        bf16x8 Bh[2], Bl[2];
#pragma unroll
        for (int nt = 0; nt < 2; ++nt) {
          const ushort* p = cpL + (size_t)(nt * 20 + ks * 2) * 512;
          Bh[nt] = *reinterpret_cast<const bf16x8*>(p);
          Bl[nt] = *reinterpret_cast<const bf16x8*>(p + 512);
        }
        if (kp < 4) {
#pragma unroll
          for (int mt = 0; mt < 3; ++mt) {
            const ushort* p = kpL + (size_t)((w * 3 + mt) * 20 + (ks + 1) * 2) * 512;
            AhA[mt] = *reinterpret_cast<const bf16x8*>(p);
            AlA[mt] = *reinterpret_cast<const bf16x8*>(p + 512);
          }
        }
#pragma unroll
        for (int mt = 0; mt < 3; ++mt)
#pragma unroll
          for (int nt = 0; nt < 2; ++nt) {
            acc[mt][nt] = MFMA16(AhB[mt], Bh[nt], acc[mt][nt]);
            acc[mt][nt] = MFMA16(AhB[mt], Bl[nt], acc[mt][nt]);
            acc[mt][nt] = MFMA16(AlB[mt], Bh[nt], acc[mt][nt]);
          }
      }
    }
#pragma unroll
    for (int mt = 0; mt < 3; ++mt)
#pragma unroll
      for (int nt = 0; nt < 2; ++nt)
#pragma unroll
        for (int r = 0; r < 4; ++r) {
          const int o = w * 48 + mt * 16 + kg * 4 + r;
          qk_s[o * 36 + nt * 16 + lrow] = acc[mt][nt][r] + bal[o];
        }
  }
  __syncthreads();

  // ---- P2: scores + softmax (fp32); write packed bf16 hi/lo attn in MFMA-B layout
  {
    const int sg = tid & 7, tq = tid >> 3;
    const int s0 = sg * 4;
    float scA[4] = {0.f, 0.f, 0.f, 0.f}, scB[4] = {0.f, 0.f, 0.f, 0.f};
#pragma unroll 8
    for (int o = 0; o < 80; o += 2) {
      const float qa = qk_s[o * 36 + tq];
      const float4 ka = *reinterpret_cast<const float4*>(&qk_s[(96 + o) * 36 + s0]);
      const float qb = qk_s[(o + 1) * 36 + tq];
      const float4 kb = *reinterpret_cast<const float4*>(&qk_s[(97 + o) * 36 + s0]);
      scA[0] = fmaf(qa, ka.x, scA[0]); scB[0] = fmaf(qb, kb.x, scB[0]);
      scA[1] = fmaf(qa, ka.y, scA[1]); scB[1] = fmaf(qb, kb.y, scB[1]);
      scA[2] = fmaf(qa, ka.z, scA[2]); scB[2] = fmaf(qb, kb.z, scB[2]);
      scA[3] = fmaf(qa, ka.w, scA[3]); scB[3] = fmaf(qb, kb.w, scB[3]);
    }
    float sc[4];
#pragma unroll
    for (int u = 0; u < 4; ++u) sc[u] = scA[u] + scB[u];
    float m = fmaxf(fmaxf(sc[0], sc[1]), fmaxf(sc[2], sc[3]));
    m = fmaxf(m, __shfl_xor(m, 1));
    m = fmaxf(m, __shfl_xor(m, 2));
    m = fmaxf(m, __shfl_xor(m, 4));
    float ev[4], ssum = 0.f;
#pragma unroll
    for (int u = 0; u < 4; ++u) { ev[u] = expf(sc[u] - m); ssum += ev[u]; }
    ssum += __shfl_xor(ssum, 1);
    ssum += __shfl_xor(ssum, 2);
    ssum += __shfl_xor(ssum, 4);
    const float inv = 1.0f / ssum;
    const int tt = tq >> 4, lrp = tq & 15, kgp = sg >> 1, eb = (sg & 1) * 4;
    ushort h4[4], l4[4];
#pragma unroll
    for (int u = 0; u < 4; ++u) {
      const float val = ev[u] * inv;
      const ushort hi = f2bf(val);
      h4[u] = hi;
      l4[u] = f2bf(val - bf2f(hi));
    }
    uint2 ph, pl2;
    ph.x = (uint)h4[0] | ((uint)h4[1] << 16);
    ph.y = (uint)h4[2] | ((uint)h4[3] << 16);
    pl2.x = (uint)l4[0] | ((uint)l4[1] << 16);
    pl2.y = (uint)l4[2] | ((uint)l4[3] << 16);
    *reinterpret_cast<uint2*>(&at_p[((tt * 2 + 0) * 64 + kgp * 16 + lrp) * 8 + eb]) = ph;
    *reinterpret_cast<uint2*>(&at_p[((tt * 2 + 1) * 64 + kgp * 16 + lrp) * 8 + eb]) = pl2;
  }
  __syncthreads();

  // ---- P3: v tiles [12,32) in 2 chunks; 1-pass bf16 proj + MFMA PV (3-pass)
  ushort* vt = reinterpret_cast<ushort*>(qk_s);
#pragma unroll
  for (int ch = 0; ch < 2; ++ch) {
    const int TB = 12 + ch * 12;
    const int RB = TB * 16;
    const int nmt = ch ? 2 : 3;
    f32x4 vacc[3][2];
#pragma unroll
    for (int a = 0; a < 3; ++a)
#pragma unroll
      for (int b2 = 0; b2 < 2; ++b2) vacc[a][b2] = (f32x4){0.f, 0.f, 0.f, 0.f};
    bf16x8 AvA[3], AvB[3];
    for (int mi = 0; mi < nmt; ++mi)
      AvA[mi] = *reinterpret_cast<const bf16x8*>(kpL + (size_t)((TB + w + mi * 4) * 20) * 512);
#pragma unroll
    for (int kp = 0; kp < 5; ++kp) {
      {
        const int ks = 2 * kp;
        bf16x8 Bh[2];
#pragma unroll
        for (int nt = 0; nt < 2; ++nt)
          Bh[nt] = *reinterpret_cast<const bf16x8*>(cpL + (size_t)(nt * 20 + ks * 2) * 512);
        for (int mi = 0; mi < nmt; ++mi)
          AvB[mi] = *reinterpret_cast<const bf16x8*>(
              kpL + (size_t)((TB + w + mi * 4) * 20 + (ks + 1) * 2) * 512);
        for (int mi = 0; mi < nmt; ++mi)
#pragma unroll
          for (int nt = 0; nt < 2; ++nt)
            vacc[mi][nt] = MFMA16(AvA[mi], Bh[nt], vacc[mi][nt]);
      }
      {
        const int ks = 2 * kp + 1;
        bf16x8 Bh[2];
#pragma unroll
        for (int nt = 0; nt < 2; ++nt)
          Bh[nt] = *reinterpret_cast<const bf16x8*>(cpL + (size_t)(nt * 20 + ks * 2) * 512);
        if (kp < 4) {
          for (int mi = 0; mi < nmt; ++mi)
            AvA[mi] = *reinterpret_cast<const bf16x8*>(
                kpL + (size_t)((TB + w + mi * 4) * 20 + (ks + 1) * 2) * 512);
        }
        for (int mi = 0; mi < nmt; ++mi)
#pragma unroll
          for (int nt = 0; nt < 2; ++nt)
            vacc[mi][nt] = MFMA16(AvB[mi], Bh[nt], vacc[mi][nt]);
      }
    }
    if (ch) __syncthreads();
    for (int mi = 0; mi < nmt; ++mi) {
      const int tile = w + mi * 4;
#pragma unroll
      for (int nt = 0; nt < 2; ++nt) {
        const int kgp = nt * 2 + (lrow >> 3), ee = lrow & 7;
#pragma unroll
        for (int r = 0; r < 4; ++r) {
          const int vl = tile * 16 + kg * 4 + r;
          const float val = vacc[mi][nt][r] + bal[RB + vl];
          const ushort hi = f2bf(val);
          vt[((tile * 2 + 0) * 64 + kgp * 16 + kg * 4 + r) * 8 + ee] = hi;
          vt[((tile * 2 + 1) * 64 + kgp * 16 + kg * 4 + r) * 8 + ee] = f2bf(val - bf2f(hi));
        }
      }
    }
    __syncthreads();
    {
      bf16x8 ah[2], al[2];
#pragma unroll
      for (int tt = 0; tt < 2; ++tt) {
        ah[tt] = *reinterpret_cast<const bf16x8*>(&at_p[((tt * 2 + 0) * 64 + lane) * 8]);
        al[tt] = *reinterpret_cast<const bf16x8*>(&at_p[((tt * 2 + 1) * 64 + lane) * 8]);
      }
      const int npw = ch ? 2 : 3;
      for (int j = 0; j < npw; ++j) {
        const int ct = w * npw + j;
        const int c0 = ch * 192 + ct * 16 + (lane >> 4) * 4;
        const bf16x8 vh  = *reinterpret_cast<const bf16x8*>(&vt[((ct * 2 + 0) * 64 + lane) * 8]);
        const bf16x8 vl8 = *reinterpret_cast<const bf16x8*>(&vt[((ct * 2 + 1) * 64 + lane) * 8]);
        f32x4 a0 = (f32x4){0.f, 0.f, 0.f, 0.f}, a1 = (f32x4){0.f, 0.f, 0.f, 0.f};
        a0 = MFMA16(vh, ah[0], a0);
        a0 = MFMA16(vh, al[0], a0);
        a0 = MFMA16(vl8, ah[0], a0);
        a1 = MFMA16(vh, ah[1], a1);
        a1 = MFMA16(vh, al[1], a1);
        a1 = MFMA16(vl8, ah[1], a1);
        if (c0 < 300) {
          const int t0 = lane & 15;
          const float4 c4a = *reinterpret_cast<const float4*>(&cap[(size_t)n * 9600 + t0 * 300 + c0]);
          const float4 c4b = *reinterpret_cast<const float4*>(&cap[(size_t)n * 9600 + (t0 + 16) * 300 + c0]);
          float mx[4];
          mx[0] = fmaxf(fmaf(gamma, a0[0], c4a.x), fmaf(gamma, a1[0], c4b.x));
          mx[1] = fmaxf(fmaf(gamma, a0[1], c4a.y), fmaf(gamma, a1[1], c4b.y));
          mx[2] = fmaxf(fmaf(gamma, a0[2], c4a.z), fmaf(gamma, a1[2], c4b.z));
          mx[3] = fmaxf(fmaf(gamma, a0[3], c4a.w), fmaf(gamma, a1[3], c4b.w));
#pragma unroll
          for (int mmask = 1; mmask < 16; mmask <<= 1)
#pragma unroll
            for (int r = 0; r < 4; ++r) mx[r] = fmaxf(mx[r], __shfl_xor(mx[r], mmask));
          if ((lane & 15) == 0)
            *reinterpret_cast<float4*>(&x_all[((size_t)i * 64 + n) * 300 + c0]) =
                make_float4(mx[0], mx[1], mx[2], mx[3]);
        }
      }
    }
  }
}

// ---------------- K5a: h1 = x @ W1^T + b1 ----------------
__global__ void __launch_bounds__(256, 4) k_h1(
    const float* __restrict__ x_all, const float* __restrict__ W1,
    const float* __restrict__ b1, float* __restrict__ h1) {
  __shared__ float xt[32 * 68];
  __shared__ float wt[32 * 132];
  const int ec = blockIdx.x, i = blockIdx.y, tid = threadIdx.x;
  const int e0c = ec * 128;
  const int eg = tid & 15, ng = tid >> 4;
  const int e0 = eg * 8, n0 = ng * 4;
  float acc[4][8] = {};
  for (int cb = 0; cb < 10; ++cb) {
    const int c0 = cb * 32;
    __syncthreads();
    for (int k = 0; k < 8; ++k) {
      const int idx = tid + 256 * k;
      const int nn = idx >> 5, cl = idx & 31;
      const int c = c0 + cl;
      xt[cl * 68 + nn] = (c < 300) ? x_all[((size_t)i * 64 + nn) * 300 + c] : 0.0f;
    }
    for (int k = 0; k < 16; ++k) {
      const int idx = tid + 256 * k;
      const int ee = idx >> 5, cl = idx & 31;
      const int c = c0 + cl;
      wt[cl * 132 + ee] = (c < 300) ? W1[(size_t)(e0c + ee) * 300 + c] : 0.0f;
    }
    __syncthreads();
#pragma unroll 4
    for (int cl = 0; cl < 32; ++cl) {
      const float4 xv = *reinterpret_cast<const float4*>(&xt[cl * 68 + n0]);
      const float4 wa = *reinterpret_cast<const float4*>(&wt[cl * 132 + e0]);
      const float4 wb = *reinterpret_cast<const float4*>(&wt[cl * 132 + e0 + 4]);
      const float xv4[4] = {xv.x, xv.y, xv.z, xv.w};
      const float wv8[8] = {wa.x, wa.y, wa.z, wa.w, wb.x, wb.y, wb.z, wb.w};
#pragma unroll
      for (int u = 0; u < 4; ++u)
#pragma unroll
        for (int v = 0; v < 8; ++v) acc[u][v] = fmaf(xv4[u], wv8[v], acc[u][v]);
    }
  }
  float b1v[8];
#pragma unroll
  for (int v = 0; v < 8; ++v) b1v[v] = b1[e0c + e0 + v];
#pragma unroll
  for (int u = 0; u < 4; ++u) {
    float* dst = h1 + ((size_t)i * 64 + n0 + u) * 512 + e0c + e0;
    *reinterpret_cast<float4*>(dst) =
        make_float4(acc[u][0] + b1v[0], acc[u][1] + b1v[1], acc[u][2] + b1v[2], acc[u][3] + b1v[3]);
    *reinterpret_cast<float4*>(dst + 4) =
        make_float4(acc[u][4] + b1v[4], acc[u][5] + b1v[5], acc[u][6] + b1v[6], acc[u][7] + b1v[7]);
  }
}

// ---------------- K5b: BN1+relu, h2, BN2+relu, out ----------------
__global__ void __launch_bounds__(256) k_mlp(
    const float* __restrict__ h1, const float* __restrict__ bn1s, const float* __restrict__ bn1b,
    const float* __restrict__ W2, const float* __restrict__ b2,
    const float* __restrict__ bn2s, const float* __restrict__ bn2b,
    const float* __restrict__ W3, const float* __restrict__ b3, float* __restrict__ out) {
  __shared__ float h1s[64 * 521];
  __shared__ float h2s[64 * 65];
  const int i = blockIdx.x, tid = threadIdx.x;
  for (int m = 0; m < 128; ++m) {
    const int idx = tid + 256 * m;
    h1s[(idx >> 9) * 521 + (idx & 511)] = h1[(size_t)i * 32768 + idx];
  }
  __syncthreads();
  for (int half = 0; half < 2; ++half) {
    const int e = tid + 256 * half;
    float s1 = 0.f, s2 = 0.f;
    for (int nn = 0; nn < 64; ++nn) {
      const float v = h1s[nn * 521 + e];
      s1 += v;
      s2 += v * v;
    }
    const float mu = s1 * (1.0f / 64.0f);
    const float var = s2 * (1.0f / 64.0f) - mu * mu;
    const float scale = bn1s[e] / sqrtf(var + EPSB);
    const float shift = bn1b[e] - mu * scale;
    for (int nn = 0; nn < 64; ++nn) {
      const float v = fmaf(h1s[nn * 521 + e], scale, shift);
      h1s[nn * 521 + e] = fmaxf(v, 0.0f);
    }
  }
  __syncthreads();
  {
    const int dg = tid & 15, ng = tid >> 4;
    const int d0 = dg * 4, n0 = ng * 4;
    float acc[4][4] = {};
#pragma unroll 2
    for (int e = 0; e < 512; ++e) {
      float h4[4], w4[4];
#pragma unroll
      for (int u = 0; u < 4; ++u) h4[u] = h1s[(n0 + u) * 521 + e];
#pragma unroll
      for (int v = 0; v < 4; ++v) w4[v] = W2[(size_t)(d0 + v) * 512 + e];
#pragma unroll
      for (int u = 0; u < 4; ++u)
#pragma unroll
        for (int v = 0; v < 4; ++v) acc[u][v] = fmaf(h4[u], w4[v], acc[u][v]);
    }
#pragma unroll
    for (int u = 0; u < 4; ++u)
#pragma unroll
      for (int v = 0; v < 4; ++v) h2s[(n0 + u) * 65 + d0 + v] = acc[u][v] + b2[d0 + v];
  }
  __syncthreads();
  if (tid < 64) {
    const int d = tid;
    float s1 = 0.f, s2 = 0.f;
    for (int nn = 0; nn < 64; ++nn) {
      const float v = h2s[nn * 65 + d];
      s1 += v;
      s2 += v * v;
    }
    const float mu = s1 * (1.0f / 64.0f);
    const float var = s2 * (1.0f / 64.0f) - mu * mu;
    const float scale = bn2s[d] / sqrtf(var + EPSB);
    const float shift = bn2b[d] - mu * scale;
    for (int nn = 0; nn < 64; ++nn)
      h2s[nn * 65 + d] = fmaxf(fmaf(h2s[nn * 65 + d], scale, shift), 0.0f);
  }
  __syncthreads();
  if (tid < 64) {
    const int nn = tid;
    float acc = b3[0];
    for (int d = 0; d < 64; ++d) acc = fmaf(h2s[nn * 65 + d], W3[d], acc);
    out[i * 64 + nn] = acc;
  }
}

extern "C" void kernel_launch(void* const* d_in, const int* in_sizes, int n_in,
                              void* d_out, int out_size, void* d_ws, size_t ws_size,
                              hipStream_t stream) {
  const float* img  = (const float*)d_in[0];
  const float* cap  = (const float*)d_in[1];
  const float* adW  = (const float*)d_in[2];
  const float* adb  = (const float*)d_in[3];
  const float* qkW  = (const float*)d_in[4];
  const float* qkb  = (const float*)d_in[5];
  const float* qbW  = (const float*)d_in[6];
  const float* qbb  = (const float*)d_in[7];
  const float* qbns = (const float*)d_in[8];
  const float* qbnb = (const float*)d_in[9];
  const float* kkW  = (const float*)d_in[10];
  const float* kkb  = (const float*)d_in[11];
  const float* kbW  = (const float*)d_in[12];
  const float* kbb  = (const float*)d_in[13];
  const float* kbns = (const float*)d_in[14];
  const float* kbnb = (const float*)d_in[15];
  const float* vkW  = (const float*)d_in[16];
  const float* vkb  = (const float*)d_in[17];
  const float* vbW  = (const float*)d_in[18];
  const float* vbb  = (const float*)d_in[19];
  const float* vbns = (const float*)d_in[20];
  const float* vbnb = (const float*)d_in[21];
  const float* gamma= (const float*)d_in[22];
  const float* W1   = (const float*)d_in[23];
  const float* b1   = (const float*)d_in[24];
  const float* bn1s = (const float*)d_in[25];
  const float* bn1b = (const float*)d_in[26];
  const float* W2   = (const float*)d_in[27];
  const float* b2   = (const float*)d_in[28];
  const float* bn2s = (const float*)d_in[29];
  const float* bn2b = (const float*)d_in[30];
  const float* W3   = (const float*)d_in[31];
  const float* b3   = (const float*)d_in[32];

  float* ws    = (float*)d_ws;
  float* base  = ws + OFS_BASE;
  float* ball  = ws + OFS_BALL;
  float* mean  = ws + OFS_MEAN;
  ushort* capP = (ushort*)(ws + OFS_CAPB);
  ushort* kall = (ushort*)(ws + OFS_RAWP);
  float* x_all = ws + OFS_X;
  float* h1    = ws + OFS_H1;    // aliases kall (dead after k_attn7)
  float* out   = (float*)d_out;

  k_mean<<<512, 256, 0, stream>>>(img, mean);
  k_base<<<128, 128, 0, stream>>>(mean, adW, adb, base);
  k_bias<<<dim3(2, 128), 256, 0, stream>>>(qbW, qbb, kbW, kbb, vbW, vbb, base, ball);
  k_capp<<<64, 256, 0, stream>>>(cap, capP);
  k_hyp2<<<dim3(512, 2), 256, 0, stream>>>(qkW, qkb, kkW, kkb, vkW, vkb,
                                           qbns, qbnb, kbns, kbnb, vbns, vbnb, base, kall);
  k_attn7<<<8192, 256, 0, stream>>>(cap, kall, capP, ball, gamma, x_all);
  k_h1<<<dim3(4, 128), 256, 0, stream>>>(x_all, W1, b1, h1);
  k_mlp<<<128, 256, 0, stream>>>(h1, bn1s, bn1b, W2, b2, bn2s, bn2b, W3, b3, out);
}